// Round 11
// baseline (279.635 us; speedup 1.0000x reference)
//
#include <hip/hip_runtime.h>
#include <math.h>

#define BATCH 2048
#define NW    16384   // neurons = 128*128
#define FEAT  256
#define SOMC  128
#define KTILES 8      // 8 K-tiles of 64 bf16 (32 hi | 32 lo)
#define SPLITK 512    // bf16 per row after hi/lo split

typedef __attribute__((ext_vector_type(8)))  short short8v;   // 8 bf16 = 4 VGPR
typedef __attribute__((ext_vector_type(16))) float f32x16;    // 32x32 MFMA acc

// ---- ws layout (frag path) ----
// xn   : 0                      2048 f32
// wn   : 8192                   16384 f32
// bmu  : 73728                  2048 u64
// xf   : 90112                  2048*512 bf16 (2 MB)   fragment-layout
// wf   : 2187264                16384*512 bf16 (16 MB) fragment-layout
#define WS_NEEDED 18964480ull

// Fragment layout (bf16-unit strides): [p][kt][hilo][ks][q5][c32][e8]
//   e:1, c32:8, q5:256, ks:512, hilo:1024, kt:2048, p:16384

static __device__ __forceinline__ unsigned short f2bf(float f) {
    unsigned u = __float_as_uint(f);
    unsigned r = u + 0x7FFFu + ((u >> 16) & 1u);  // RNE
    return (unsigned short)(r >> 16);
}

// ---------------- prep: norms + bmu init + hi/lo split into FRAGMENT layout ----------------
__global__ __launch_bounds__(256) void som_prep_split(const float* __restrict__ x,
                                                      const float* __restrict__ w,
                                                      float* __restrict__ xn,
                                                      float* __restrict__ wn,
                                                      unsigned long long* __restrict__ bmu,
                                                      unsigned short* __restrict__ xf,
                                                      unsigned short* __restrict__ wf) {
    const int wv = threadIdx.x >> 6;
    const int lane = threadIdx.x & 63;
    const int row = blockIdx.x * 4 + wv;            // 0 .. 18431
    const bool isx = row < BATCH;
    const float* src = isx ? x + (size_t)row * FEAT
                           : w + (size_t)(row - BATCH) * FEAT;
    float4 v = ((const float4*)src)[lane];          // k = lane*4 .. +3
    float s = v.x * v.x + v.y * v.y + v.z * v.z + v.w * v.w;
    #pragma unroll
    for (int o = 32; o; o >>= 1) s += __shfl_xor(s, o, 64);

    float fx[4] = {v.x, v.y, v.z, v.w};
    unsigned short h[4], l[4];
    #pragma unroll
    for (int i = 0; i < 4; ++i) {
        h[i] = f2bf(fx[i]);
        float hf = __uint_as_float((unsigned)h[i] << 16);
        l[i] = f2bf(fx[i] - hf);
    }
    const int lr = isx ? row : row - BATCH;
    const int k  = lane * 4;
    const int kt = k >> 5, ko = k & 31;
    const int ks = ko >> 4, q5 = (ko >> 3) & 1, e = ko & 7;
    unsigned short* base = (isx ? xf : wf)
        + (size_t)(lr >> 5) * 16384 + (size_t)kt * 2048
        + ks * 512 + q5 * 256 + (lr & 31) * 8 + e;
    *(ushort4*)(base)        = make_ushort4(h[0], h[1], h[2], h[3]);  // hilo=0
    *(ushort4*)(base + 1024) = make_ushort4(l[0], l[1], l[2], l[3]);  // hilo=1

    if (lane == 0) {
        if (isx) { xn[row] = s; bmu[row] = 0xFFFFFFFFFFFFFFFFULL; }
        else     { wn[row - BATCH] = s; }
    }
}

// ------- main MFMA kernel: 64x1024 block (write-dense), LDS-less fragment streaming -------
__global__ __launch_bounds__(256, 4) void som_mfma(const unsigned short* __restrict__ xf,
                                                   const unsigned short* __restrict__ wf,
                                                   const float* __restrict__ xn,
                                                   const float* __restrict__ wn,
                                                   float* __restrict__ out,
                                                   unsigned long long* __restrict__ bmu) {
    // Tile 64 rows x 1024 cols: per output row this block writes 4 KB (8x denser
    // DRAM-page locality than 128x128's 512 B) -- attacks the measured ~1.1 TB/s
    // scatter-write ceiling that bounded r3-r10. Grid (16,32) x-fastest: each XCD
    // gets 2 w-col-tiles (2 MB) + x (2 MB) = L2-resident operands; nt stores keep
    // the write stream out of L2 (r9/r10: FETCH 22 MB).
    const int brow = blockIdx.y * 64;
    const int bcol = blockIdx.x * 1024;

    const int t = threadIdx.x;
    const int lane = t & 63, wv = t >> 6;
    const int c32 = lane & 31, q5 = lane >> 5;

    // A fragments: rows brow..brow+63, shared by all 4 waves (L1-served on reuse).
    const unsigned short* A0 = xf + (size_t)(brow >> 5) * 16384 + lane * 8;
    const unsigned short* A1 = A0 + 16384;   // rows +32

    // wave wv owns cols [bcol + wv*256, +256), processed as 4 x 64-col sub-GEMMs
    #pragma unroll 1
    for (int csub = 0; csub < 4; ++csub) {
        const int ccol = wv * 256 + csub * 64;
        const unsigned short* B0 = wf + (size_t)((bcol + ccol) >> 5) * 16384 + lane * 8;
        const unsigned short* B1 = B0 + 16384;   // cols +32

        f32x16 zz;
        #pragma unroll
        for (int i = 0; i < 16; ++i) zz[i] = 0.0f;
        f32x16 acc00 = zz, acc01 = zz, acc10 = zz, acc11 = zz;

        #pragma unroll
        for (int kt = 0; kt < KTILES; ++kt) {
            const int kb = kt * 2048;
            #pragma unroll
            for (int ks = 0; ks < 2; ++ks) {
                const int hb = kb + ks * 512;          // hilo=0
                const int lb = hb + 1024;              // hilo=1
                short8v ah0 = *(const short8v*)(A0 + hb);
                short8v ah1 = *(const short8v*)(A1 + hb);
                short8v al0 = *(const short8v*)(A0 + lb);
                short8v al1 = *(const short8v*)(A1 + lb);
                short8v bh0 = *(const short8v*)(B0 + hb);
                short8v bh1 = *(const short8v*)(B1 + hb);
                short8v bl0 = *(const short8v*)(B0 + lb);
                short8v bl1 = *(const short8v*)(B1 + lb);
                // hh
                acc00 = __builtin_amdgcn_mfma_f32_32x32x16_bf16(ah0, bh0, acc00, 0, 0, 0);
                acc01 = __builtin_amdgcn_mfma_f32_32x32x16_bf16(ah0, bh1, acc01, 0, 0, 0);
                acc10 = __builtin_amdgcn_mfma_f32_32x32x16_bf16(ah1, bh0, acc10, 0, 0, 0);
                acc11 = __builtin_amdgcn_mfma_f32_32x32x16_bf16(ah1, bh1, acc11, 0, 0, 0);
                // hl
                acc00 = __builtin_amdgcn_mfma_f32_32x32x16_bf16(ah0, bl0, acc00, 0, 0, 0);
                acc01 = __builtin_amdgcn_mfma_f32_32x32x16_bf16(ah0, bl1, acc01, 0, 0, 0);
                acc10 = __builtin_amdgcn_mfma_f32_32x32x16_bf16(ah1, bl0, acc10, 0, 0, 0);
                acc11 = __builtin_amdgcn_mfma_f32_32x32x16_bf16(ah1, bl1, acc11, 0, 0, 0);
                // lh  (ll term ~2^-18 relative: dropped)
                acc00 = __builtin_amdgcn_mfma_f32_32x32x16_bf16(al0, bh0, acc00, 0, 0, 0);
                acc01 = __builtin_amdgcn_mfma_f32_32x32x16_bf16(al0, bh1, acc01, 0, 0, 0);
                acc10 = __builtin_amdgcn_mfma_f32_32x32x16_bf16(al1, bh0, acc10, 0, 0, 0);
                acc11 = __builtin_amdgcn_mfma_f32_32x32x16_bf16(al1, bh1, acc11, 0, 0, 0);
            }
        }

        // ---- per-csub epilogue: nt stores (interleaved with compute across csubs)
        //      + full-precision u64 argmin (r8 proved: never quantize the key) ----
        // 32x32 C/D mapping (m74/m101): col = lane&31, row = (reg&3)+8*(reg>>2)+4*(lane>>5)
        #pragma unroll
        for (int m = 0; m < 2; ++m) {
            const f32x16 a0 = m ? acc10 : acc00;
            const f32x16 a1 = m ? acc11 : acc01;
            #pragma unroll
            for (int reg = 0; reg < 16; ++reg) {
                const int rg = brow + m * 32 + (reg & 3) + 8 * (reg >> 2) + 4 * q5;
                const float xv = xn[rg];
                unsigned long long best = 0xFFFFFFFFFFFFFFFFULL;
                #pragma unroll
                for (int n = 0; n < 2; ++n) {
                    const int cg = bcol + ccol + n * 32 + c32;
                    const float dot = n ? a1[reg] : a0[reg];
                    float d2 = fmaxf(xv + wn[cg] - 2.0f * dot, 0.0f);
                    float d = sqrtf(d2);
                    __builtin_nontemporal_store(d, &out[(size_t)rg * NW + cg]);
                    unsigned long long p =
                        ((unsigned long long)__float_as_uint(d) << 32) | (unsigned)cg;
                    if (p < best) best = p;
                }
                #pragma unroll
                for (int o = 16; o; o >>= 1) {       // stays within 32-lane half
                    unsigned long long ob = __shfl_xor(best, o, 64);
                    if (ob < best) best = ob;
                }
                if (c32 == 0) atomicMin(&bmu[rg], best);
            }
        }
    }
}

// ---------------- fallback f32 path (round-1, known-passing) ----------------
#define BM  128
#define BN  128
#define BK  32
#define LDK 36

__global__ __launch_bounds__(256) void som_prep(const float* __restrict__ x,
                                                const float* __restrict__ w,
                                                float* __restrict__ xn,
                                                float* __restrict__ wn,
                                                unsigned long long* __restrict__ bmu) {
    const int wave = threadIdx.x >> 6;
    const int lane = threadIdx.x & 63;
    const int row  = blockIdx.x * 4 + wave;
    const float* src = (row < BATCH) ? (x + (size_t)row * FEAT)
                                     : (w + (size_t)(row - BATCH) * FEAT);
    float4 v = ((const float4*)src)[lane];
    float s = v.x * v.x + v.y * v.y + v.z * v.z + v.w * v.w;
    #pragma unroll
    for (int off = 32; off >= 1; off >>= 1) s += __shfl_xor(s, off, 64);
    if (lane == 0) {
        if (row < BATCH) { xn[row] = s; bmu[row] = 0xFFFFFFFFFFFFFFFFULL; }
        else             { wn[row - BATCH] = s; }
    }
}

__global__ __launch_bounds__(256) void som_f32main(const float* __restrict__ x,
                                                   const float* __restrict__ w,
                                                   const float* __restrict__ xn,
                                                   const float* __restrict__ wn,
                                                   float* __restrict__ out,
                                                   unsigned long long* __restrict__ bmu) {
    __shared__ float xs[BM][LDK];
    __shared__ float wsh[BN][LDK];
    const int t  = threadIdx.x;
    const int tx = t & 15;
    const int ty = t >> 4;
    const int brow = blockIdx.y * BM;
    const int bcol = blockIdx.x * BN;
    float acc[8][8];
    #pragma unroll
    for (int i = 0; i < 8; ++i)
        #pragma unroll
        for (int j = 0; j < 8; ++j) acc[i][j] = 0.0f;
    for (int k0 = 0; k0 < FEAT; k0 += BK) {
        #pragma unroll
        for (int r = 0; r < 4; ++r) {
            const int flat = (t + r * 256) * 4;
            const int row  = flat >> 5;
            const int col  = flat & 31;
            float4 xv = *(const float4*)&x[(size_t)(brow + row) * FEAT + k0 + col];
            float4 wv = *(const float4*)&w[(size_t)(bcol + row) * FEAT + k0 + col];
            *(float4*)&xs[row][col]  = xv;
            *(float4*)&wsh[row][col] = wv;
        }
        __syncthreads();
        #pragma unroll
        for (int kq = 0; kq < BK / 4; ++kq) {
            float4 a[8], b[8];
            #pragma unroll
            for (int i = 0; i < 8; ++i) a[i] = *(const float4*)&xs[ty + 16 * i][kq * 4];
            #pragma unroll
            for (int j = 0; j < 8; ++j) b[j] = *(const float4*)&wsh[tx + 16 * j][kq * 4];
            #pragma unroll
            for (int i = 0; i < 8; ++i)
                #pragma unroll
                for (int j = 0; j < 8; ++j) {
                    acc[i][j] += a[i].x * b[j].x;
                    acc[i][j] += a[i].y * b[j].y;
                    acc[i][j] += a[i].z * b[j].z;
                    acc[i][j] += a[i].w * b[j].w;
                }
        }
        __syncthreads();
    }
    #pragma unroll
    for (int i = 0; i < 8; ++i) {
        const int rg = brow + ty + 16 * i;
        const float xnv = xn[rg];
        unsigned long long best = 0xFFFFFFFFFFFFFFFFULL;
        #pragma unroll
        for (int j = 0; j < 8; ++j) {
            const int cg = bcol + tx + 16 * j;
            float d2 = xnv + wn[cg] - 2.0f * acc[i][j];
            d2 = fmaxf(d2, 0.0f);
            float d = sqrtf(d2);
            out[(size_t)rg * NW + cg] = d;
            unsigned long long p =
                ((unsigned long long)__float_as_uint(d) << 32) | (unsigned int)cg;
            if (p < best) best = p;
        }
        #pragma unroll
        for (int off = 8; off >= 1; off >>= 1) {
            unsigned long long o = __shfl_xor(best, off, 64);
            if (o < best) best = o;
        }
        if (tx == 0) atomicMin(&bmu[rg], best);
    }
}

__global__ __launch_bounds__(256) void som_bmu_write(const unsigned long long* __restrict__ bmu,
                                                     float* __restrict__ outb) {
    const int i = blockIdx.x * blockDim.x + threadIdx.x;
    if (i >= BATCH) return;
    const unsigned int idx = (unsigned int)(bmu[i] & 0xFFFFFFFFu);
    outb[(size_t)i * 2 + 0] = (float)(idx >> 7);
    outb[(size_t)i * 2 + 1] = (float)(idx & (SOMC - 1));
}

extern "C" void kernel_launch(void* const* d_in, const int* in_sizes, int n_in,
                              void* d_out, int out_size, void* d_ws, size_t ws_size,
                              hipStream_t stream) {
    const float* x = (const float*)d_in[0];
    const float* w = (const float*)d_in[1];
    float* out = (float*)d_out;

    float* xn = (float*)d_ws;
    float* wn = xn + BATCH;
    unsigned long long* bmu = (unsigned long long*)((char*)d_ws + 73728);
    float* outb = out + (size_t)BATCH * NW;

    if (ws_size >= WS_NEEDED) {
        unsigned short* xf = (unsigned short*)((char*)d_ws + 90112);
        unsigned short* wf = (unsigned short*)((char*)d_ws + 2187264);
        som_prep_split<<<(BATCH + NW) / 4, 256, 0, stream>>>(x, w, xn, wn, bmu, xf, wf);
        dim3 grid(NW / 1024, BATCH / 64);   // 16 x 32 = 512 blocks (write-dense tiles)
        som_mfma<<<grid, 256, 0, stream>>>(xf, wf, xn, wn, out, bmu);
    } else {
        som_prep<<<(BATCH + NW) / 4, 256, 0, stream>>>(x, w, xn, wn, bmu);
        dim3 grid(NW / BN, BATCH / BM);
        som_f32main<<<grid, 256, 0, stream>>>(x, w, xn, wn, out, bmu);
    }
    som_bmu_write<<<(BATCH + 255) / 256, 256, 0, stream>>>(bmu, outb);
}